// Round 12
// baseline (1439.889 us; speedup 1.0000x reference)
//
#include <hip/hip_runtime.h>
#include <hip/hip_fp16.h>

#define TOTAL 131072
#define SEGN  256
#define FEAT  78
#define FPAD  96
#define HID   1024
#define NCLS  10
#define FCHUNK 32

typedef __attribute__((ext_vector_type(8))) short short8;
typedef __attribute__((ext_vector_type(4))) float floatx4;

typedef __attribute__((address_space(1))) void gvoid_t;
typedef __attribute__((address_space(3))) void svoid_t;

__device__ __forceinline__ void async_copy16(const void* gsrc, void* ldst) {
    __builtin_amdgcn_global_load_lds((gvoid_t*)(void*)gsrc, (svoid_t*)ldst, 16, 0, 0);
}

// ---------------- conversion kernels ----------------

// W [K,N] fp32 row-major -> Wt [N,Kpad] fp16 row-major (transposed, zero-padded K)
__global__ void conv_wt_kernel(const float* __restrict__ W, __half* __restrict__ Wt,
                               int K, int N, int Kpad) {
    int idx = blockIdx.x * 256 + threadIdx.x;
    if (idx >= N * Kpad) return;
    int k = idx % Kpad;
    int n = idx / Kpad;
    float v = (k < K) ? W[(size_t)k * N + n] : 0.0f;
    Wt[idx] = __float2half(v);
}

// 4x HIDxHID weight transpose+cvt in one dispatch (blockIdx.y selects weight)
__global__ void conv_w4_kernel(const float* __restrict__ W2, const float* __restrict__ W3,
                               const float* __restrict__ W4, const float* __restrict__ W6,
                               __half* __restrict__ w2t, __half* __restrict__ w3t,
                               __half* __restrict__ w4t, __half* __restrict__ w6t) {
    int idx = blockIdx.x * 256 + threadIdx.x;
    if (idx >= HID * HID) return;
    int k = idx % HID;
    int n = idx / HID;
    const float* Ws[4] = {W2, W3, W4, W6};
    __half* Ts[4] = {w2t, w3t, w4t, w6t};
    int w = blockIdx.y;
    Ts[w][idx] = __float2half(Ws[w][(size_t)k * HID + n]);
}

// ---------------- main GEMM: C = act(A @ Bt^T + bias) ----------------
// R8 structure: 128x128 tile, BK=64 as two BK=32 buffer pairs (one barrier pair
// per 64 k), A+B staged via global_load_lds, XCD swizzle, LDS-repack epilogue.
// Optional fused attention-score partial dot (scores_p != 0): each column-block
// writes its partial row-dot with W5 to scores_p[bn*M + row] (plain store).

__global__ __launch_bounds__(256, 2)
void gemm_f16(const __half* __restrict__ A, const __half* __restrict__ Bt,
              __half* __restrict__ C, const float* __restrict__ bias,
              int M, int N, int K, int relu_flag,
              const float* __restrict__ W5g, float* __restrict__ scores_p)
{
    __shared__ __align__(16) short smem[4 * 128 * 32];   // 32 KB: A0,A1,B0,B1
    short* lds_a0 = smem;
    short* lds_a1 = smem + 128 * 32;
    short* lds_b0 = smem + 2 * 128 * 32;
    short* lds_b1 = smem + 3 * 128 * 32;

    const int t   = threadIdx.x;
    const int nbn = N >> 7;
    const int nbm = M >> 7;
    int bm, bn;
    {
        const int b = blockIdx.x;
        if ((nbm & 7) == 0) {
            const int xcd = b & 7;
            const int j   = b >> 3;
            bm = xcd * (nbm >> 3) + j / nbn;   // contiguous bm range per XCD
            bn = j % nbn;                      // bn-fast within XCD -> A-stripe reuse
        } else {
            bn = b % nbn;
            bm = b / nbn;
        }
    }
    const size_t m0 = (size_t)bm * 128;
    const size_t n0 = (size_t)bn * 128;
    const int wave = t >> 6, lane = t & 63;
    const int wm = (wave >> 1) << 6;
    const int wn = (wave & 1) << 6;
    const int l16 = lane & 15, q = lane >> 4;

    floatx4 acc[4][4] = {};

    // staging chunk c (16B = 8 f16): row = c>>2, k-slot = c&3
    const int c0 = t, c1 = t + 256;
    const __half* a0 = A  + (m0 + (size_t)(c0 >> 2)) * K + (c0 & 3) * 8;
    const __half* a1 = A  + (m0 + (size_t)(c1 >> 2)) * K + (c1 & 3) * 8;
    const __half* b0 = Bt + (n0 + (size_t)(c0 >> 2)) * K + (c0 & 3) * 8;
    const __half* b1 = Bt + (n0 + (size_t)(c1 >> 2)) * K + (c1 & 3) * 8;
    short* lA0_0 = &lds_a0[c0 * 8];
    short* lA0_1 = &lds_a0[c1 * 8];
    short* lA1_0 = &lds_a1[c0 * 8];
    short* lA1_1 = &lds_a1[c1 * 8];
    short* lB0_0 = &lds_b0[c0 * 8];
    short* lB0_1 = &lds_b0[c1 * 8];
    short* lB1_0 = &lds_b1[c0 * 8];
    short* lB1_1 = &lds_b1[c1 * 8];

    for (int k0 = 0; k0 < K; k0 += 64) {
        __syncthreads();
        async_copy16(a0 + k0, lA0_0);
        async_copy16(a1 + k0, lA0_1);
        async_copy16(b0 + k0, lB0_0);
        async_copy16(b1 + k0, lB0_1);
        async_copy16(a0 + k0 + 32, lA1_0);
        async_copy16(a1 + k0 + 32, lA1_1);
        async_copy16(b0 + k0 + 32, lB1_0);
        async_copy16(b1 + k0 + 32, lB1_1);
        __syncthreads();

        short8 af[4], bf[4];
#pragma unroll
        for (int i = 0; i < 4; ++i)
            af[i] = *(const short8*)&lds_a0[(wm + i * 16 + l16) * 32 + q * 8];
#pragma unroll
        for (int i = 0; i < 4; ++i)
            bf[i] = *(const short8*)&lds_b0[(wn + i * 16 + l16) * 32 + q * 8];
#pragma unroll
        for (int mi = 0; mi < 4; ++mi)
#pragma unroll
            for (int ni = 0; ni < 4; ++ni)
                acc[mi][ni] = __builtin_amdgcn_mfma_f32_16x16x32_f16(
                    af[mi], bf[ni], acc[mi][ni], 0, 0, 0);

#pragma unroll
        for (int i = 0; i < 4; ++i)
            af[i] = *(const short8*)&lds_a1[(wm + i * 16 + l16) * 32 + q * 8];
#pragma unroll
        for (int i = 0; i < 4; ++i)
            bf[i] = *(const short8*)&lds_b1[(wn + i * 16 + l16) * 32 + q * 8];
#pragma unroll
        for (int mi = 0; mi < 4; ++mi)
#pragma unroll
            for (int ni = 0; ni < 4; ++ni)
                acc[mi][ni] = __builtin_amdgcn_mfma_f32_16x16x32_f16(
                    af[mi], bf[ni], acc[mi][ni], 0, 0, 0);
    }

    // ---- epilogue: two 64-row rounds through LDS, 16B coalesced stores ----
    __half* ct = (__half*)smem;
#pragma unroll
    for (int h = 0; h < 2; ++h) {
        __syncthreads();
        if (wm == h * 64) {
#pragma unroll
            for (int ni = 0; ni < 4; ++ni) {
                const int col = wn + ni * 16 + l16;
                const float bv = bias[n0 + col];
#pragma unroll
                for (int mi = 0; mi < 4; ++mi) {
                    const int r0l = mi * 16 + q * 4;
#pragma unroll
                    for (int r = 0; r < 4; ++r) {
                        float v = acc[mi][ni][r] + bv;
                        if (relu_flag) v = fmaxf(v, 0.0f);
                        ct[(r0l + r) * 128 + col] = __float2half(v);
                    }
                }
            }
        }
        __syncthreads();
#pragma unroll
        for (int it = 0; it < 4; ++it) {
            const int chunk = it * 256 + t;
            const int row = chunk >> 4;
            const int off = (chunk & 15) * 8;
            short8 v = *(const short8*)&ct[row * 128 + off];
            *(short8*)&C[(m0 + h * 64 + row) * N + n0 + off] = v;
            if (scores_p) {
                // partial attention-score dot: 8 cols of this row x W5
                const float* wv = W5g + n0 + off;
                float p = 0.f;
#pragma unroll
                for (int j = 0; j < 8; ++j)
                    p += __half2float(((const __half*)&v)[j]) * wv[j];
#pragma unroll
                for (int o = 8; o > 0; o >>= 1) p += __shfl_down(p, o, 16);
                if (l16 == 0)
                    scores_p[(size_t)bn * M + m0 + h * 64 + row] = p;
            }
        }
    }
}

// ---------------- layer-1 GEMM: K=96, fused fp32->fp16 x staging --------------
// Reads x (fp32, [TOTAL,78]) directly; converts+zero-pads to 96 cols in LDS.

__global__ __launch_bounds__(256, 2)
void gemm_k96(const float* __restrict__ X, int row0, const __half* __restrict__ Bt,
              __half* __restrict__ C, const float* __restrict__ bias, int M, int N)
{
    __shared__ __align__(16) short smem[2 * 128 * 96];   // 48 KB
    short* lds_a = smem;
    short* lds_b = smem + 128 * 96;

    const int t   = threadIdx.x;
    const int nbn = N >> 7;
    const int nbm = M >> 7;
    int bm, bn;
    {
        const int b = blockIdx.x;
        if ((nbm & 7) == 0) {
            const int xcd = b & 7;
            const int j   = b >> 3;
            bm = xcd * (nbm >> 3) + j / nbn;
            bn = j % nbn;
        } else {
            bn = b % nbn;
            bm = b / nbn;
        }
    }
    const size_t m0 = (size_t)bm * 128;
    const size_t n0 = (size_t)bn * 128;
    const int wave = t >> 6, lane = t & 63;
    const int wm = (wave >> 1) << 6;
    const int wn = (wave & 1) << 6;
    const int l16 = lane & 15, q = lane >> 4;

    // staging: 1536 16B-chunks per matrix, 6 per thread: row = c/12, slot = c%12
#pragma unroll
    for (int i = 0; i < 6; ++i) {
        const int c = i * 256 + t;
        const int r = c / 12, j = c % 12;
        // A: convert fp32 x row on the fly (zero-pad cols >= FEAT)
        const float* xr = X + (size_t)(row0 + m0 + r) * FEAT + j * 8;
        __half tmp[8];
#pragma unroll
        for (int jj = 0; jj < 8; ++jj) {
            const int col = j * 8 + jj;
            tmp[jj] = __float2half(col < FEAT ? xr[jj] : 0.0f);
        }
        *(short8*)&lds_a[c * 8] = *(const short8*)tmp;
        async_copy16(Bt + (n0 + (size_t)r) * 96 + j * 8, &lds_b[c * 8]);
    }
    __syncthreads();

    floatx4 acc[4][4] = {};
#pragma unroll
    for (int ks = 0; ks < 3; ++ks) {
        short8 af[4], bf[4];
        const int xo = ks * 32 + q * 8;
#pragma unroll
        for (int i = 0; i < 4; ++i)
            af[i] = *(const short8*)&lds_a[(wm + i * 16 + l16) * 96 + xo];
#pragma unroll
        for (int i = 0; i < 4; ++i)
            bf[i] = *(const short8*)&lds_b[(wn + i * 16 + l16) * 96 + xo];
#pragma unroll
        for (int mi = 0; mi < 4; ++mi)
#pragma unroll
            for (int ni = 0; ni < 4; ++ni)
                acc[mi][ni] = __builtin_amdgcn_mfma_f32_16x16x32_f16(
                    af[mi], bf[ni], acc[mi][ni], 0, 0, 0);
    }

    __half* ct = (__half*)smem;
#pragma unroll
    for (int h = 0; h < 2; ++h) {
        __syncthreads();
        if (wm == h * 64) {
#pragma unroll
            for (int ni = 0; ni < 4; ++ni) {
                const int col = wn + ni * 16 + l16;
                const float bv = bias[n0 + col];
#pragma unroll
                for (int mi = 0; mi < 4; ++mi) {
                    const int r0l = mi * 16 + q * 4;
#pragma unroll
                    for (int r = 0; r < 4; ++r) {
                        float v = fmaxf(acc[mi][ni][r] + bv, 0.0f);
                        ct[(r0l + r) * 128 + col] = __float2half(v);
                    }
                }
            }
        }
        __syncthreads();
#pragma unroll
        for (int it = 0; it < 4; ++it) {
            const int chunk = it * 256 + t;
            const int row = chunk >> 4;
            const int off = (chunk & 15) * 8;
            *(short8*)&C[(m0 + h * 64 + row) * N + n0 + off] =
                *(const short8*)&ct[row * 128 + off];
        }
    }
}

// ---------------- segment offsets ----------------

__global__ void seg_offsets_kernel(const int* __restrict__ lengths, int* __restrict__ off) {
    if (blockIdx.x == 0 && threadIdx.x == 0) {
        int a = 0;
        off[0] = 0;
        for (int i = 0; i < SEGN; ++i) { a += lengths[i]; off[i + 1] = a; }
    }
}

// ---------------- pooling (score partials from layer-4 GEMM epilogue) ---------
// Block = 32-frame chunk. score = sum of 8 column-block partials;
// e = exp(relu(score+b5)); weighted column pool; denom via <=2 atomics/block.

__global__ __launch_bounds__(256)
void scorepool_kernel(const __half* __restrict__ h4, int slab_beg, int slab_rows,
                      const float* __restrict__ scores_p, const float* __restrict__ b5,
                      const int* __restrict__ segoff,
                      float* __restrict__ pooled, float* __restrict__ denom)
{
    __shared__ float e_sh[FCHUNK];
    const int t = threadIdx.x;
    const int f0 = slab_beg + blockIdx.x * FCHUNK;

    if (t < FCHUNK) {
        const int fl = f0 - slab_beg + t;   // slab-local frame
        float sc = 0.f;
#pragma unroll
        for (int b = 0; b < 8; ++b) sc += scores_p[(size_t)b * slab_rows + fl];
        sc = fmaxf(sc + b5[0], 0.0f);
        e_sh[t] = __expf(fminf(sc, 80.0f));
    }
    __syncthreads();

    const int c0 = t * 4;
    int lo = 0, hi = SEGN - 1;
    while (lo < hi) {
        int mid = (lo + hi + 1) >> 1;
        if (segoff[mid] <= f0) lo = mid; else hi = mid - 1;
    }
    int s = lo;
    int f = f0;
    const int fend = f0 + FCHUNK;
    const __half* base = h4 + (size_t)(f0 - slab_beg) * HID + c0;
    while (f < fend) {
        int send = segoff[s + 1];
        if (send > fend) send = fend;
        float a0 = 0.f, a1 = 0.f, a2 = 0.f, a3 = 0.f, es = 0.f;
        for (; f < send; ++f, base += HID) {
            float e = e_sh[f - f0];
            const __half2* r2 = (const __half2*)base;
            float2 u = __half22float2(r2[0]);
            float2 v = __half22float2(r2[1]);
            a0 += e * u.x; a1 += e * u.y; a2 += e * v.x; a3 += e * v.y;
            es += e;
        }
        float* p = pooled + (size_t)s * HID + c0;
        atomicAdd(p,     a0);
        atomicAdd(p + 1, a1);
        atomicAdd(p + 2, a2);
        atomicAdd(p + 3, a3);
        if (t == 0) atomicAdd(&denom[s], es);
        ++s;
    }
}

// ---------------- finalize: divide + fp16 ----------------

__global__ __launch_bounds__(256)
void finalize_pool_kernel(const float* __restrict__ pooled, const float* __restrict__ denom,
                          __half* __restrict__ poolh)
{
    int s = blockIdx.x, t = threadIdx.x;
    float inv = 1.0f / denom[s];
    for (int j = t; j < HID; j += 256)
        poolh[(size_t)s * HID + j] = __float2half(pooled[(size_t)s * HID + j] * inv);
}

// ---------------- final head: out = z @ W7 + b7 ----------------

__global__ void final_kernel(const __half* __restrict__ z, const float* __restrict__ W7,
                             const float* __restrict__ b7, float* __restrict__ out) {
    int s = blockIdx.x, t = threadIdx.x;
    float loc[NCLS];
#pragma unroll
    for (int c = 0; c < NCLS; ++c) loc[c] = 0.f;
    for (int k = t; k < HID; k += 256) {
        float zk = __half2float(z[(size_t)s * HID + k]);
        const float* wr = W7 + k * NCLS;
#pragma unroll
        for (int c = 0; c < NCLS; ++c) loc[c] += zk * wr[c];
    }
#pragma unroll
    for (int c = 0; c < NCLS; ++c)
#pragma unroll
        for (int o = 32; o > 0; o >>= 1) loc[c] += __shfl_down(loc[c], o);
    __shared__ float accs[NCLS];
    if (t < NCLS) accs[t] = 0.f;
    __syncthreads();
    if ((t & 63) == 0)
        for (int c = 0; c < NCLS; ++c) atomicAdd(&accs[c], loc[c]);
    __syncthreads();
    if (t < NCLS) out[s * NCLS + t] = accs[t] + b7[t];
}

// ---------------- launch ----------------

extern "C" void kernel_launch(void* const* d_in, const int* in_sizes, int n_in,
                              void* d_out, int out_size, void* d_ws, size_t ws_size,
                              hipStream_t stream) {
    const float* x  = (const float*)d_in[0];
    const float* W1 = (const float*)d_in[1];
    const float* b1 = (const float*)d_in[2];
    const float* W2 = (const float*)d_in[3];
    const float* b2 = (const float*)d_in[4];
    const float* W3 = (const float*)d_in[5];
    const float* b3 = (const float*)d_in[6];
    const float* W4 = (const float*)d_in[7];
    const float* b4 = (const float*)d_in[8];
    const float* W5 = (const float*)d_in[9];
    const float* b5 = (const float*)d_in[10];
    const float* W6 = (const float*)d_in[11];
    const float* b6 = (const float*)d_in[12];
    const float* W7 = (const float*)d_in[13];
    const float* b7 = (const float*)d_in[14];
    const int* lengths = (const int*)d_in[15];
    float* out = (float*)d_out;

    char* ws = (char*)d_ws;
    size_t off = 0;
    auto take = [&](size_t bytes) -> char* {
        char* p = ws + off;
        off = (off + bytes + 255) & ~(size_t)255;
        return p;
    };
    __half* w1t   = (__half*)take((size_t)HID * FPAD * 2);
    __half* w2t   = (__half*)take((size_t)HID * HID * 2);
    __half* w3t   = (__half*)take((size_t)HID * HID * 2);
    __half* w4t   = (__half*)take((size_t)HID * HID * 2);
    __half* w6t   = (__half*)take((size_t)HID * HID * 2);
    int*    segoff = (int*)take((SEGN + 1) * 4);
    float*  pooled = (float*)take((size_t)SEGN * HID * 4);
    float*  denom  = (float*)take(SEGN * 4);
    __half* poolh  = (__half*)take((size_t)SEGN * HID * 2);
    __half* z      = (__half*)take((size_t)SEGN * HID * 2);

    // slab rows: largest power-of-two divisor of TOTAL that fits
    // per-R need: slabA + slabB (fp16) + scores_p (8 x R fp32)
    int R = TOTAL;
    while (R > 1024) {
        size_t need = off + 2 * (size_t)R * HID * 2 + (size_t)8 * R * 4 + 3 * 256;
        if (need <= ws_size) break;
        R >>= 1;
    }
    __half* slabA    = (__half*)take((size_t)R * HID * 2);
    __half* slabB    = (__half*)take((size_t)R * HID * 2);
    float*  scores_p = (float*)take((size_t)8 * R * 4);

    seg_offsets_kernel<<<1, 64, 0, stream>>>(lengths, segoff);
    hipMemsetAsync(pooled, 0, (size_t)SEGN * HID * 4, stream);
    hipMemsetAsync(denom, 0, SEGN * 4, stream);

    conv_wt_kernel<<<(HID * FPAD + 255) / 256, 256, 0, stream>>>(W1, w1t, FEAT, HID, FPAD);
    dim3 gW((HID * HID + 255) / 256, 4);
    conv_w4_kernel<<<gW, 256, 0, stream>>>(W2, W3, W4, W6, w2t, w3t, w4t, w6t);

    const int nBlocksSlab = (R / 128) * (HID / 128);
    for (int sb = 0; sb < TOTAL; sb += R) {
        gemm_k96<<<nBlocksSlab, 256, 0, stream>>>(x, sb, w1t, slabA, b1, R, HID);
        gemm_f16<<<nBlocksSlab, 256, 0, stream>>>(slabA, w2t, slabB, b2, R, HID, HID, 1,
                                                  nullptr, nullptr);
        gemm_f16<<<nBlocksSlab, 256, 0, stream>>>(slabB, w3t, slabA, b3, R, HID, HID, 1,
                                                  nullptr, nullptr);
        // layer-4: partial scores per column-block -> scores_p[bn*R + slabRow]
        gemm_f16<<<nBlocksSlab, 256, 0, stream>>>(slabA, w4t, slabB, b4, R, HID, HID, 1,
                                                  W5, scores_p);
        scorepool_kernel<<<R / FCHUNK, 256, 0, stream>>>(slabB, sb, R, scores_p, b5,
                                                         segoff, pooled, denom);
    }

    finalize_pool_kernel<<<SEGN, 256, 0, stream>>>(pooled, denom, poolh);
    const int nBlocksHead = (SEGN / 128) * (HID / 128);
    gemm_f16<<<nBlocksHead, 256, 0, stream>>>(poolh, w6t, z, b6, SEGN, HID, HID, 1,
                                              nullptr, nullptr);
    final_kernel<<<SEGN, 256, 0, stream>>>(z, W7, b7, out);
}

// Round 13
// 1284.537 us; speedup vs baseline: 1.1209x; 1.1209x over previous
//
#include <hip/hip_runtime.h>
#include <hip/hip_fp16.h>

#define TOTAL 131072
#define SEGN  256
#define FEAT  78
#define FPAD  96
#define HID   1024
#define NCLS  10
#define FCHUNK 32

typedef __attribute__((ext_vector_type(8))) short short8;
typedef __attribute__((ext_vector_type(4))) float floatx4;

typedef __attribute__((address_space(1))) void gvoid_t;
typedef __attribute__((address_space(3))) void svoid_t;

__device__ __forceinline__ void async_copy16(const void* gsrc, void* ldst) {
    __builtin_amdgcn_global_load_lds((gvoid_t*)(void*)gsrc, (svoid_t*)ldst, 16, 0, 0);
}

// ---------------- conversion kernels ----------------

// x slab [rows, FEAT] fp32 -> [rows, FPAD] fp16 (zero-padded cols), coalesced, once per slab
__global__ void conv_x_slab(const float* __restrict__ x, __half* __restrict__ xb,
                            int row0, int rows) {
    int idx = blockIdx.x * 256 + threadIdx.x;
    if (idx >= rows * FPAD) return;
    int col = idx % FPAD;
    int r   = idx / FPAD;
    float v = (col < FEAT) ? x[(size_t)(row0 + r) * FEAT + col] : 0.0f;
    xb[idx] = __float2half(v);
}

// W [K,N] fp32 row-major -> Wt [N,Kpad] fp16 row-major (transposed, zero-padded K)
__global__ void conv_wt_kernel(const float* __restrict__ W, __half* __restrict__ Wt,
                               int K, int N, int Kpad) {
    int idx = blockIdx.x * 256 + threadIdx.x;
    if (idx >= N * Kpad) return;
    int k = idx % Kpad;
    int n = idx / Kpad;
    float v = (k < K) ? W[(size_t)k * N + n] : 0.0f;
    Wt[idx] = __float2half(v);
}

// 4x HIDxHID weight transpose+cvt in one dispatch (blockIdx.y selects weight)
__global__ void conv_w4_kernel(const float* __restrict__ W2, const float* __restrict__ W3,
                               const float* __restrict__ W4, const float* __restrict__ W6,
                               __half* __restrict__ w2t, __half* __restrict__ w3t,
                               __half* __restrict__ w4t, __half* __restrict__ w6t) {
    int idx = blockIdx.x * 256 + threadIdx.x;
    if (idx >= HID * HID) return;
    int k = idx % HID;
    int n = idx / HID;
    const float* Ws[4] = {W2, W3, W4, W6};
    __half* Ts[4] = {w2t, w3t, w4t, w6t};
    int w = blockIdx.y;
    Ts[w][idx] = __float2half(Ws[w][(size_t)k * HID + n]);
}

// ---------------- main GEMM: C = act(A @ Bt^T + bias) ----------------
// R8 structure: 128x128 tile, BK=64 as two BK=32 buffer pairs (one barrier pair
// per 64 k), A+B staged via global_load_lds, XCD swizzle, LDS-repack epilogue.
// Optional fused attention-score partial dot (scores_p != 0): each column-block
// writes its partial row-dot with W5 to scores_p[bn*M + row] (plain store).

__global__ __launch_bounds__(256, 2)
void gemm_f16(const __half* __restrict__ A, const __half* __restrict__ Bt,
              __half* __restrict__ C, const float* __restrict__ bias,
              int M, int N, int K, int relu_flag,
              const float* __restrict__ W5g, float* __restrict__ scores_p)
{
    __shared__ __align__(16) short smem[4 * 128 * 32];   // 32 KB: A0,A1,B0,B1
    short* lds_a0 = smem;
    short* lds_a1 = smem + 128 * 32;
    short* lds_b0 = smem + 2 * 128 * 32;
    short* lds_b1 = smem + 3 * 128 * 32;

    const int t   = threadIdx.x;
    const int nbn = N >> 7;
    const int nbm = M >> 7;
    int bm, bn;
    {
        const int b = blockIdx.x;
        if ((nbm & 7) == 0) {
            const int xcd = b & 7;
            const int j   = b >> 3;
            bm = xcd * (nbm >> 3) + j / nbn;   // contiguous bm range per XCD
            bn = j % nbn;                      // bn-fast within XCD -> A-stripe reuse
        } else {
            bn = b % nbn;
            bm = b / nbn;
        }
    }
    const size_t m0 = (size_t)bm * 128;
    const size_t n0 = (size_t)bn * 128;
    const int wave = t >> 6, lane = t & 63;
    const int wm = (wave >> 1) << 6;
    const int wn = (wave & 1) << 6;
    const int l16 = lane & 15, q = lane >> 4;

    floatx4 acc[4][4] = {};

    // staging chunk c (16B = 8 f16): row = c>>2, k-slot = c&3
    const int c0 = t, c1 = t + 256;
    const __half* a0 = A  + (m0 + (size_t)(c0 >> 2)) * K + (c0 & 3) * 8;
    const __half* a1 = A  + (m0 + (size_t)(c1 >> 2)) * K + (c1 & 3) * 8;
    const __half* b0 = Bt + (n0 + (size_t)(c0 >> 2)) * K + (c0 & 3) * 8;
    const __half* b1 = Bt + (n0 + (size_t)(c1 >> 2)) * K + (c1 & 3) * 8;
    short* lA0_0 = &lds_a0[c0 * 8];
    short* lA0_1 = &lds_a0[c1 * 8];
    short* lA1_0 = &lds_a1[c0 * 8];
    short* lA1_1 = &lds_a1[c1 * 8];
    short* lB0_0 = &lds_b0[c0 * 8];
    short* lB0_1 = &lds_b0[c1 * 8];
    short* lB1_0 = &lds_b1[c0 * 8];
    short* lB1_1 = &lds_b1[c1 * 8];

    for (int k0 = 0; k0 < K; k0 += 64) {
        __syncthreads();
        async_copy16(a0 + k0, lA0_0);
        async_copy16(a1 + k0, lA0_1);
        async_copy16(b0 + k0, lB0_0);
        async_copy16(b1 + k0, lB0_1);
        async_copy16(a0 + k0 + 32, lA1_0);
        async_copy16(a1 + k0 + 32, lA1_1);
        async_copy16(b0 + k0 + 32, lB1_0);
        async_copy16(b1 + k0 + 32, lB1_1);
        __syncthreads();

        short8 af[4], bf[4];
#pragma unroll
        for (int i = 0; i < 4; ++i)
            af[i] = *(const short8*)&lds_a0[(wm + i * 16 + l16) * 32 + q * 8];
#pragma unroll
        for (int i = 0; i < 4; ++i)
            bf[i] = *(const short8*)&lds_b0[(wn + i * 16 + l16) * 32 + q * 8];
#pragma unroll
        for (int mi = 0; mi < 4; ++mi)
#pragma unroll
            for (int ni = 0; ni < 4; ++ni)
                acc[mi][ni] = __builtin_amdgcn_mfma_f32_16x16x32_f16(
                    af[mi], bf[ni], acc[mi][ni], 0, 0, 0);

#pragma unroll
        for (int i = 0; i < 4; ++i)
            af[i] = *(const short8*)&lds_a1[(wm + i * 16 + l16) * 32 + q * 8];
#pragma unroll
        for (int i = 0; i < 4; ++i)
            bf[i] = *(const short8*)&lds_b1[(wn + i * 16 + l16) * 32 + q * 8];
#pragma unroll
        for (int mi = 0; mi < 4; ++mi)
#pragma unroll
            for (int ni = 0; ni < 4; ++ni)
                acc[mi][ni] = __builtin_amdgcn_mfma_f32_16x16x32_f16(
                    af[mi], bf[ni], acc[mi][ni], 0, 0, 0);
    }

    // ---- epilogue: two 64-row rounds through LDS, 16B coalesced stores ----
    __half* ct = (__half*)smem;
#pragma unroll
    for (int h = 0; h < 2; ++h) {
        __syncthreads();
        if (wm == h * 64) {
#pragma unroll
            for (int ni = 0; ni < 4; ++ni) {
                const int col = wn + ni * 16 + l16;
                const float bv = bias[n0 + col];
#pragma unroll
                for (int mi = 0; mi < 4; ++mi) {
                    const int r0l = mi * 16 + q * 4;
#pragma unroll
                    for (int r = 0; r < 4; ++r) {
                        float v = acc[mi][ni][r] + bv;
                        if (relu_flag) v = fmaxf(v, 0.0f);
                        ct[(r0l + r) * 128 + col] = __float2half(v);
                    }
                }
            }
        }
        __syncthreads();
#pragma unroll
        for (int it = 0; it < 4; ++it) {
            const int chunk = it * 256 + t;
            const int row = chunk >> 4;
            const int off = (chunk & 15) * 8;
            short8 v = *(const short8*)&ct[row * 128 + off];
            *(short8*)&C[(m0 + h * 64 + row) * N + n0 + off] = v;
            if (scores_p) {
                // partial attention-score dot: 8 cols of this row x W5
                const float* wv = W5g + n0 + off;
                float p = 0.f;
#pragma unroll
                for (int j = 0; j < 8; ++j)
                    p += __half2float(((const __half*)&v)[j]) * wv[j];
#pragma unroll
                for (int o = 8; o > 0; o >>= 1) p += __shfl_down(p, o, 16);
                if (l16 == 0)
                    scores_p[(size_t)bn * M + m0 + h * 64 + row] = p;
            }
        }
    }
}

// ---------------- layer-1 GEMM: K=96, single staging round (R8 form) ---------

__global__ __launch_bounds__(256, 2)
void gemm_k96(const __half* __restrict__ A, const __half* __restrict__ Bt,
              __half* __restrict__ C, const float* __restrict__ bias, int M, int N)
{
    __shared__ __align__(16) short smem[2 * 128 * 96];   // 48 KB
    short* lds_a = smem;
    short* lds_b = smem + 128 * 96;

    const int t   = threadIdx.x;
    const int nbn = N >> 7;
    const int nbm = M >> 7;
    int bm, bn;
    {
        const int b = blockIdx.x;
        if ((nbm & 7) == 0) {
            const int xcd = b & 7;
            const int j   = b >> 3;
            bm = xcd * (nbm >> 3) + j / nbn;
            bn = j % nbn;
        } else {
            bn = b % nbn;
            bm = b / nbn;
        }
    }
    const size_t m0 = (size_t)bm * 128;
    const size_t n0 = (size_t)bn * 128;
    const int wave = t >> 6, lane = t & 63;
    const int wm = (wave >> 1) << 6;
    const int wn = (wave & 1) << 6;
    const int l16 = lane & 15, q = lane >> 4;

#pragma unroll
    for (int i = 0; i < 6; ++i) {
        const int c = i * 256 + t;
        const int r = c / 12, j = c % 12;
        async_copy16(A  + (m0 + (size_t)r) * 96 + j * 8, &lds_a[c * 8]);
        async_copy16(Bt + (n0 + (size_t)r) * 96 + j * 8, &lds_b[c * 8]);
    }
    __syncthreads();

    floatx4 acc[4][4] = {};
#pragma unroll
    for (int ks = 0; ks < 3; ++ks) {
        short8 af[4], bf[4];
        const int xo = ks * 32 + q * 8;
#pragma unroll
        for (int i = 0; i < 4; ++i)
            af[i] = *(const short8*)&lds_a[(wm + i * 16 + l16) * 96 + xo];
#pragma unroll
        for (int i = 0; i < 4; ++i)
            bf[i] = *(const short8*)&lds_b[(wn + i * 16 + l16) * 96 + xo];
#pragma unroll
        for (int mi = 0; mi < 4; ++mi)
#pragma unroll
            for (int ni = 0; ni < 4; ++ni)
                acc[mi][ni] = __builtin_amdgcn_mfma_f32_16x16x32_f16(
                    af[mi], bf[ni], acc[mi][ni], 0, 0, 0);
    }

    __half* ct = (__half*)smem;
#pragma unroll
    for (int h = 0; h < 2; ++h) {
        __syncthreads();
        if (wm == h * 64) {
#pragma unroll
            for (int ni = 0; ni < 4; ++ni) {
                const int col = wn + ni * 16 + l16;
                const float bv = bias[n0 + col];
#pragma unroll
                for (int mi = 0; mi < 4; ++mi) {
                    const int r0l = mi * 16 + q * 4;
#pragma unroll
                    for (int r = 0; r < 4; ++r) {
                        float v = fmaxf(acc[mi][ni][r] + bv, 0.0f);
                        ct[(r0l + r) * 128 + col] = __float2half(v);
                    }
                }
            }
        }
        __syncthreads();
#pragma unroll
        for (int it = 0; it < 4; ++it) {
            const int chunk = it * 256 + t;
            const int row = chunk >> 4;
            const int off = (chunk & 15) * 8;
            *(short8*)&C[(m0 + h * 64 + row) * N + n0 + off] =
                *(const short8*)&ct[row * 128 + off];
        }
    }
}

// ---------------- segment offsets ----------------

__global__ void seg_offsets_kernel(const int* __restrict__ lengths, int* __restrict__ off) {
    if (blockIdx.x == 0 && threadIdx.x == 0) {
        int a = 0;
        off[0] = 0;
        for (int i = 0; i < SEGN; ++i) { a += lengths[i]; off[i + 1] = a; }
    }
}

// ---------------- pooling (score partials from layer-4 GEMM epilogue) ---------
// Block = 32-frame chunk. score = sum of 8 column-block partials;
// e = exp(relu(score+b5)); weighted column pool; denom via <=2 atomics/block.

__global__ __launch_bounds__(256)
void scorepool_kernel(const __half* __restrict__ h4, int slab_beg, int slab_rows,
                      const float* __restrict__ scores_p, const float* __restrict__ b5,
                      const int* __restrict__ segoff,
                      float* __restrict__ pooled, float* __restrict__ denom)
{
    __shared__ float e_sh[FCHUNK];
    const int t = threadIdx.x;
    const int f0 = slab_beg + blockIdx.x * FCHUNK;

    if (t < FCHUNK) {
        const int fl = f0 - slab_beg + t;   // slab-local frame
        float sc = 0.f;
#pragma unroll
        for (int b = 0; b < 8; ++b) sc += scores_p[(size_t)b * slab_rows + fl];
        sc = fmaxf(sc + b5[0], 0.0f);
        e_sh[t] = __expf(fminf(sc, 80.0f));
    }
    __syncthreads();

    const int c0 = t * 4;
    int lo = 0, hi = SEGN - 1;
    while (lo < hi) {
        int mid = (lo + hi + 1) >> 1;
        if (segoff[mid] <= f0) lo = mid; else hi = mid - 1;
    }
    int s = lo;
    int f = f0;
    const int fend = f0 + FCHUNK;
    const __half* base = h4 + (size_t)(f0 - slab_beg) * HID + c0;
    while (f < fend) {
        int send = segoff[s + 1];
        if (send > fend) send = fend;
        float a0 = 0.f, a1 = 0.f, a2 = 0.f, a3 = 0.f, es = 0.f;
        for (; f < send; ++f, base += HID) {
            float e = e_sh[f - f0];
            const __half2* r2 = (const __half2*)base;
            float2 u = __half22float2(r2[0]);
            float2 v = __half22float2(r2[1]);
            a0 += e * u.x; a1 += e * u.y; a2 += e * v.x; a3 += e * v.y;
            es += e;
        }
        float* p = pooled + (size_t)s * HID + c0;
        atomicAdd(p,     a0);
        atomicAdd(p + 1, a1);
        atomicAdd(p + 2, a2);
        atomicAdd(p + 3, a3);
        if (t == 0) atomicAdd(&denom[s], es);
        ++s;
    }
}

// ---------------- finalize: divide + fp16 ----------------

__global__ __launch_bounds__(256)
void finalize_pool_kernel(const float* __restrict__ pooled, const float* __restrict__ denom,
                          __half* __restrict__ poolh)
{
    int s = blockIdx.x, t = threadIdx.x;
    float inv = 1.0f / denom[s];
    for (int j = t; j < HID; j += 256)
        poolh[(size_t)s * HID + j] = __float2half(pooled[(size_t)s * HID + j] * inv);
}

// ---------------- final head: out = z @ W7 + b7 ----------------

__global__ void final_kernel(const __half* __restrict__ z, const float* __restrict__ W7,
                             const float* __restrict__ b7, float* __restrict__ out) {
    int s = blockIdx.x, t = threadIdx.x;
    float loc[NCLS];
#pragma unroll
    for (int c = 0; c < NCLS; ++c) loc[c] = 0.f;
    for (int k = t; k < HID; k += 256) {
        float zk = __half2float(z[(size_t)s * HID + k]);
        const float* wr = W7 + k * NCLS;
#pragma unroll
        for (int c = 0; c < NCLS; ++c) loc[c] += zk * wr[c];
    }
#pragma unroll
    for (int c = 0; c < NCLS; ++c)
#pragma unroll
        for (int o = 32; o > 0; o >>= 1) loc[c] += __shfl_down(loc[c], o);
    __shared__ float accs[NCLS];
    if (t < NCLS) accs[t] = 0.f;
    __syncthreads();
    if ((t & 63) == 0)
        for (int c = 0; c < NCLS; ++c) atomicAdd(&accs[c], loc[c]);
    __syncthreads();
    if (t < NCLS) out[s * NCLS + t] = accs[t] + b7[t];
}

// ---------------- launch ----------------

extern "C" void kernel_launch(void* const* d_in, const int* in_sizes, int n_in,
                              void* d_out, int out_size, void* d_ws, size_t ws_size,
                              hipStream_t stream) {
    const float* x  = (const float*)d_in[0];
    const float* W1 = (const float*)d_in[1];
    const float* b1 = (const float*)d_in[2];
    const float* W2 = (const float*)d_in[3];
    const float* b2 = (const float*)d_in[4];
    const float* W3 = (const float*)d_in[5];
    const float* b3 = (const float*)d_in[6];
    const float* W4 = (const float*)d_in[7];
    const float* b4 = (const float*)d_in[8];
    const float* W5 = (const float*)d_in[9];
    const float* b5 = (const float*)d_in[10];
    const float* W6 = (const float*)d_in[11];
    const float* b6 = (const float*)d_in[12];
    const float* W7 = (const float*)d_in[13];
    const float* b7 = (const float*)d_in[14];
    const int* lengths = (const int*)d_in[15];
    float* out = (float*)d_out;

    char* ws = (char*)d_ws;
    size_t off = 0;
    auto take = [&](size_t bytes) -> char* {
        char* p = ws + off;
        off = (off + bytes + 255) & ~(size_t)255;
        return p;
    };
    __half* w1t   = (__half*)take((size_t)HID * FPAD * 2);
    __half* w2t   = (__half*)take((size_t)HID * HID * 2);
    __half* w3t   = (__half*)take((size_t)HID * HID * 2);
    __half* w4t   = (__half*)take((size_t)HID * HID * 2);
    __half* w6t   = (__half*)take((size_t)HID * HID * 2);
    int*    segoff = (int*)take((SEGN + 1) * 4);
    float*  pooled = (float*)take((size_t)SEGN * HID * 4);
    float*  denom  = (float*)take(SEGN * 4);
    __half* poolh  = (__half*)take((size_t)SEGN * HID * 2);
    __half* z      = (__half*)take((size_t)SEGN * HID * 2);

    // slab rows: largest power-of-two divisor of TOTAL that fits
    // per-R need: slabX (fp16 xpad) + slabA + slabB + scores_p (8 x R fp32)
    int R = TOTAL;
    while (R > 1024) {
        size_t need = off + (size_t)R * FPAD * 2 + 2 * (size_t)R * HID * 2
                    + (size_t)8 * R * 4 + 4 * 256;
        if (need <= ws_size) break;
        R >>= 1;
    }
    __half* slabX    = (__half*)take((size_t)R * FPAD * 2);
    __half* slabA    = (__half*)take((size_t)R * HID * 2);
    __half* slabB    = (__half*)take((size_t)R * HID * 2);
    float*  scores_p = (float*)take((size_t)8 * R * 4);

    seg_offsets_kernel<<<1, 64, 0, stream>>>(lengths, segoff);
    hipMemsetAsync(pooled, 0, (size_t)SEGN * HID * 4, stream);
    hipMemsetAsync(denom, 0, SEGN * 4, stream);

    conv_wt_kernel<<<(HID * FPAD + 255) / 256, 256, 0, stream>>>(W1, w1t, FEAT, HID, FPAD);
    dim3 gW((HID * HID + 255) / 256, 4);
    conv_w4_kernel<<<gW, 256, 0, stream>>>(W2, W3, W4, W6, w2t, w3t, w4t, w6t);

    const int nBlocksSlab = (R / 128) * (HID / 128);
    for (int sb = 0; sb < TOTAL; sb += R) {
        conv_x_slab<<<(R * FPAD + 255) / 256, 256, 0, stream>>>(x, slabX, sb, R);
        gemm_k96<<<nBlocksSlab, 256, 0, stream>>>(slabX, w1t, slabA, b1, R, HID);
        gemm_f16<<<nBlocksSlab, 256, 0, stream>>>(slabA, w2t, slabB, b2, R, HID, HID, 1,
                                                  nullptr, nullptr);
        gemm_f16<<<nBlocksSlab, 256, 0, stream>>>(slabB, w3t, slabA, b3, R, HID, HID, 1,
                                                  nullptr, nullptr);
        // layer-4: partial scores per column-block -> scores_p[bn*R + slabRow]
        gemm_f16<<<nBlocksSlab, 256, 0, stream>>>(slabA, w4t, slabB, b4, R, HID, HID, 1,
                                                  W5, scores_p);
        scorepool_kernel<<<R / FCHUNK, 256, 0, stream>>>(slabB, sb, R, scores_p, b5,
                                                         segoff, pooled, denom);
    }

    finalize_pool_kernel<<<SEGN, 256, 0, stream>>>(pooled, denom, poolh);
    const int nBlocksHead = (SEGN / 128) * (HID / 128);
    gemm_f16<<<nBlocksHead, 256, 0, stream>>>(poolh, w6t, z, b6, SEGN, HID, HID, 1,
                                              nullptr, nullptr);
    final_kernel<<<SEGN, 256, 0, stream>>>(z, W7, b7, out);
}